// Round 9
// baseline (3760.481 us; speedup 1.0000x reference)
//
#include <hip/hip_runtime.h>
#include <hip/hip_bf16.h>
#include <math.h>

#define B_ 2
#define T_ 2048
#define C_ 1024
#define H_ 16
#define D_ 64
#define CS_ 64
#define NC_ 32
#define NS_ 5
#define IST 136   // interleaved row stride in shorts (64 elems * 2 + 8 pad; 16B-aligned)

typedef __attribute__((ext_vector_type(8))) short bf16x8;
typedef __attribute__((ext_vector_type(4))) float f32x4;

__device__ inline void split2(float x, unsigned short& h, unsigned short& l) {
    __hip_bfloat16 bh = __float2bfloat16(x);           // hw cvt
    float lo = x - __bfloat162float(bh);
    __hip_bfloat16 bl = __float2bfloat16(lo);
    h = __builtin_bit_cast(unsigned short, bh);
    l = __builtin_bit_cast(unsigned short, bl);
}

// ---------------------------------------------------------------------------
// split f32 -> (hi, lo) bf16 buffers
// ---------------------------------------------------------------------------
__global__ __launch_bounds__(256) void split_kernel(const float* __restrict__ src,
                                                    unsigned short* __restrict__ hi,
                                                    unsigned short* __restrict__ lo,
                                                    int n) {
    int i = (blockIdx.x * 256 + threadIdx.x) * 4;
    if (i >= n) return;
    float4 v = *(const float4*)&src[i];
    unsigned short h0, l0, h1, l1, h2, l2, h3, l3;
    split2(v.x, h0, l0); split2(v.y, h1, l1);
    split2(v.z, h2, l2); split2(v.w, h3, l3);
    uint2 hv = make_uint2((unsigned)h0 | ((unsigned)h1 << 16), (unsigned)h2 | ((unsigned)h3 << 16));
    uint2 lv = make_uint2((unsigned)l0 | ((unsigned)l1 << 16), (unsigned)l2 | ((unsigned)l3 << 16));
    *(uint2*)&hi[i] = hv;
    *(uint2*)&lo[i] = lv;
}

// ---------------------------------------------------------------------------
// Split-precision bf16 MFMA GEMM (unchanged).
// ---------------------------------------------------------------------------
__global__ __launch_bounds__(256, 1) void gemm_split(const unsigned short* __restrict__ Ah,
                                                     const unsigned short* __restrict__ Al,
                                                     const unsigned short* __restrict__ Bh,
                                                     const unsigned short* __restrict__ Bl,
                                                     float* __restrict__ out) {
    __shared__ __align__(16) unsigned short sAh[128 * 72];
    __shared__ __align__(16) unsigned short sAl[128 * 72];
    __shared__ __align__(16) unsigned short sBh[128 * 72];
    __shared__ __align__(16) unsigned short sBl[128 * 72];
    int tid = threadIdx.x;
    int m0 = blockIdx.y * 128, n0 = blockIdx.x * 128;
    int w = tid >> 6, lane = tid & 63, q = lane >> 4, c = lane & 15;
    int mq = (w >> 1) * 64, nq = (w & 1) * 64;
    f32x4 acc[4][4];
    #pragma unroll
    for (int i = 0; i < 4; i++)
        #pragma unroll
        for (int j = 0; j < 4; j++) acc[i][j] = (f32x4){0.f, 0.f, 0.f, 0.f};
    int lrow = tid >> 2, lseg = (tid & 3) * 16;
    for (int kt = 0; kt < C_; kt += 64) {
        #pragma unroll
        for (int rr = 0; rr < 2; rr++) {
            int row = lrow + rr * 64;
            const size_t ga = (size_t)(m0 + row) * C_ + kt + lseg;
            const size_t gb = (size_t)(n0 + row) * C_ + kt + lseg;
            bf16x8 vah0 = *(const bf16x8*)&Ah[ga];
            bf16x8 vah1 = *(const bf16x8*)&Ah[ga + 8];
            bf16x8 val0 = *(const bf16x8*)&Al[ga];
            bf16x8 val1 = *(const bf16x8*)&Al[ga + 8];
            bf16x8 vbh0 = *(const bf16x8*)&Bh[gb];
            bf16x8 vbh1 = *(const bf16x8*)&Bh[gb + 8];
            bf16x8 vbl0 = *(const bf16x8*)&Bl[gb];
            bf16x8 vbl1 = *(const bf16x8*)&Bl[gb + 8];
            *(bf16x8*)&sAh[row * 72 + lseg] = vah0;
            *(bf16x8*)&sAh[row * 72 + lseg + 8] = vah1;
            *(bf16x8*)&sAl[row * 72 + lseg] = val0;
            *(bf16x8*)&sAl[row * 72 + lseg + 8] = val1;
            *(bf16x8*)&sBh[row * 72 + lseg] = vbh0;
            *(bf16x8*)&sBh[row * 72 + lseg + 8] = vbh1;
            *(bf16x8*)&sBl[row * 72 + lseg] = vbl0;
            *(bf16x8*)&sBl[row * 72 + lseg + 8] = vbl1;
        }
        __syncthreads();
        #pragma unroll
        for (int t = 0; t < 2; t++) {
            bf16x8 af[4][2], bfr[4][2];
            #pragma unroll
            for (int i = 0; i < 4; i++) {
                af[i][0] = *(const bf16x8*)&sAh[(mq + 16 * i + c) * 72 + t * 32 + q * 8];
                af[i][1] = *(const bf16x8*)&sAl[(mq + 16 * i + c) * 72 + t * 32 + q * 8];
            }
            #pragma unroll
            for (int j = 0; j < 4; j++) {
                bfr[j][0] = *(const bf16x8*)&sBh[(nq + 16 * j + c) * 72 + t * 32 + q * 8];
                bfr[j][1] = *(const bf16x8*)&sBl[(nq + 16 * j + c) * 72 + t * 32 + q * 8];
            }
            #pragma unroll
            for (int i = 0; i < 4; i++)
                #pragma unroll
                for (int j = 0; j < 4; j++) {
                    acc[i][j] = __builtin_amdgcn_mfma_f32_16x16x32_bf16(af[i][0], bfr[j][0], acc[i][j], 0, 0, 0);
                    acc[i][j] = __builtin_amdgcn_mfma_f32_16x16x32_bf16(af[i][0], bfr[j][1], acc[i][j], 0, 0, 0);
                    acc[i][j] = __builtin_amdgcn_mfma_f32_16x16x32_bf16(af[i][1], bfr[j][0], acc[i][j], 0, 0, 0);
                }
        }
        __syncthreads();
    }
    #pragma unroll
    for (int i = 0; i < 4; i++)
        #pragma unroll
        for (int j = 0; j < 4; j++)
            #pragma unroll
            for (int r = 0; r < 4; r++)
                out[(size_t)(m0 + mq + 16 * i + 4 * q + r) * C_ + n0 + nq + 16 * j + c] = acc[i][j][r];
}

// ---------------------------------------------------------------------------
// Causal depthwise conv (K=4) + optional per-head RMS norm + optional poly.
// ---------------------------------------------------------------------------
__global__ __launch_bounds__(256) void conv_kernel(const float* __restrict__ xin,
                                                   const float* __restrict__ w,
                                                   const float* __restrict__ bias,
                                                   float* __restrict__ out, int mode) {
    int bt = blockIdx.x;
    int t = bt & (T_ - 1);
    int tid = threadIdx.x;
    int c0 = tid * 4;
    float4 w4[4];
    #pragma unroll
    for (int i = 0; i < 4; i++) w4[i] = *(const float4*)&w[(c0 + i) * 4];
    float4 bi = *(const float4*)&bias[c0];
    float4 xs[4];
    #pragma unroll
    for (int j = 0; j < 4; j++) {
        int tt = t - 3 + j;
        xs[j] = (tt >= 0) ? *(const float4*)&xin[(bt - 3 + j) * C_ + c0]
                          : make_float4(0.f, 0.f, 0.f, 0.f);
    }
    float y0 = bi.x + w4[0].x * xs[0].x + w4[0].y * xs[1].x + w4[0].z * xs[2].x + w4[0].w * xs[3].x;
    float y1 = bi.y + w4[1].x * xs[0].y + w4[1].y * xs[1].y + w4[1].z * xs[2].y + w4[1].w * xs[3].y;
    float y2 = bi.z + w4[2].x * xs[0].z + w4[2].y * xs[1].z + w4[2].z * xs[2].z + w4[2].w * xs[3].z;
    float y3 = bi.w + w4[3].x * xs[0].w + w4[3].y * xs[1].w + w4[3].z * xs[2].w + w4[3].w * xs[3].w;
    if (mode >= 1) {
        float ss = y0 * y0 + y1 * y1 + y2 * y2 + y3 * y3;
        ss += __shfl_xor(ss, 1);
        ss += __shfl_xor(ss, 2);
        ss += __shfl_xor(ss, 4);
        ss += __shfl_xor(ss, 8);
        float sc = rsqrtf(ss * (1.f / 64.f) + 1e-6f);
        y0 *= sc; y1 *= sc; y2 *= sc; y3 *= sc;
        if (mode == 2) {
            y0 += 0.5f * y0 * y0; y1 += 0.5f * y1 * y1;
            y2 += 0.5f * y2 * y2; y3 += 0.5f * y3 * y3;
        }
    }
    *(float4*)&out[bt * C_ + c0] = make_float4(y0, y1, y2, y3);
}

// ---------------------------------------------------------------------------
// Gate projections.
// ---------------------------------------------------------------------------
__global__ __launch_bounds__(256) void gates_kernel(const float* __restrict__ x,
                                                    const float* __restrict__ Wa,
                                                    const float* __restrict__ We,
                                                    const float* __restrict__ Wt,
                                                    const float* __restrict__ Wg,
                                                    float* __restrict__ gates) {
    __shared__ float xs[C_];
    int bt = blockIdx.x, tid = threadIdx.x;
    *(float4*)&xs[tid * 4] = *(const float4*)&x[bt * C_ + tid * 4];
    __syncthreads();
    int dot = tid >> 2, l = tid & 3;
    int g = dot >> 4, h = dot & 15;
    const float* Wp = (g == 0) ? Wa : (g == 1) ? We : (g == 2) ? Wt : Wg;
    const float* Wr = Wp + h * C_;
    float p = 0.f;
    for (int c = l * 4; c < C_; c += 16) {
        float4 wv = *(const float4*)&Wr[c];
        float4 xv = *(const float4*)&xs[c];
        p += wv.x * xv.x + wv.y * xv.y + wv.z * xv.z + wv.w * xv.w;
    }
    p += __shfl_xor(p, 1);
    p += __shfl_xor(p, 2);
    if (l == 0) gates[g * (B_ * T_ * H_) + bt * H_ + h] = 1.f / (1.f + __expf(-p));
}

// ---------------------------------------------------------------------------
// chunk_s: standalone (chunk 0 only) — unchanged.
// ---------------------------------------------------------------------------
__global__ __launch_bounds__(256) void chunk_s_kernel(const float* __restrict__ kbuf,
                                                      const float* __restrict__ vbuf,
                                                      const float* __restrict__ gates,
                                                      const float* __restrict__ Mc,
                                                      float* __restrict__ Sc,
                                                      float* __restrict__ chunkS,
                                                      int chunk) {
    __shared__ float Kc[CS_][68];
    __shared__ float Mrow[8][68];
    __shared__ float errS[CS_][8];
    __shared__ float thS[CS_], etS[CS_], gmS[CS_];
    int tid = threadIdx.x;
    int idx = blockIdx.x;
    int vt = idx & 7, h = (idx >> 3) & 15, b = idx >> 7;
    int c0t = chunk * CS_;
    {
        int row = tid >> 2, col = (tid & 3) * 16;
        const float* src = &kbuf[((size_t)(b * T_ + c0t + row) * H_ + h) * D_];
        #pragma unroll
        for (int i = 0; i < 4; i++)
            *(float4*)&Kc[row][col + i * 4] = *(const float4*)&src[col + i * 4];
    }
    if (tid < 128) {
        int v = tid >> 4, cc = (tid & 15) * 4;
        *(float4*)&Mrow[v][cc] =
            *(const float4*)&Mc[((size_t)(b * H_ + h)) * 4096 + (vt * 8 + v) * 64 + cc];
    }
    if (tid < CS_)           thS[tid] = gates[2 * (B_ * T_ * H_) + (b * T_ + c0t + tid) * H_ + h];
    else if (tid < 2 * CS_)  { int t = tid - CS_;     etS[t] = gates[1 * (B_ * T_ * H_) + (b * T_ + c0t + t) * H_ + h]; }
    else if (tid < 3 * CS_)  { int t = tid - 2 * CS_; gmS[t] = gates[3 * (B_ * T_ * H_) + (b * T_ + c0t + t) * H_ + h]; }
    __syncthreads();
    {
        int t = tid >> 2, v0 = (tid & 3) * 2;
        float s0 = 0.f, s1 = 0.f;
        #pragma unroll
        for (int k = 0; k < 64; k += 4) {
            float4 kv = *(float4*)&Kc[t][k];
            float4 m0 = *(float4*)&Mrow[v0][k];
            float4 m1 = *(float4*)&Mrow[v0 + 1][k];
            s0 += kv.x * m0.x + kv.y * m0.y + kv.z * m0.z + kv.w * m0.w;
            s1 += kv.x * m1.x + kv.y * m1.y + kv.z * m1.z + kv.w * m1.w;
        }
        const float* vp = &vbuf[((size_t)(b * T_ + c0t + t) * H_ + h) * D_ + vt * 8 + v0];
        errS[t][v0]     = s0 - vp[0];
        errS[t][v0 + 1] = s1 - vp[1];
    }
    __syncthreads();
    int vl = tid >> 5;
    int kk = (tid & 31) * 2;
    size_t sIdx = ((size_t)(b * H_ + h)) * 4096 + (vt * 8 + vl) * 64 + kk;
    float S0 = Sc[sIdx], S1 = Sc[sIdx + 1];
    float ring0[16] = {}, ring1[16] = {};
    float cum0 = 0.f, cum1 = 0.f;
    for (int cb = 0; cb < 4; ++cb) {
        #pragma unroll
        for (int ci = 0; ci < 16; ++ci) {
            int c = cb * 16 + ci;
            float er = 2.f * errS[c][vl];
            float2 kv = *(float2*)&Kc[c][kk];
            float g = gmS[c];
            cum0 += g * er * kv.x;
            cum1 += g * er * kv.y;
            float uw0 = cum0 - ring0[ci];
            float uw1 = cum1 - ring1[ci];
            ring0[ci] = cum0; ring1[ci] = cum1;
            float th = thS[c], et = etS[c];
            S0 = th * S0 - et * uw0;
            S1 = th * S1 - et * uw1;
            size_t o = ((size_t)((b * H_ + h) * CS_ + c)) * 4096 + (vt * 8 + vl) * 64 + kk;
            *(float2*)&chunkS[o] = make_float2(S0, S1);
        }
    }
    Sc[sIdx] = S0; Sc[sIdx + 1] = S1;
}

// ---------------------------------------------------------------------------
// Polar-Express — unchanged from round 8 (quadrant ownership, 4 barriers).
// ---------------------------------------------------------------------------
__device__ inline bf16x8 swap16(bf16x8 v) {
    union { bf16x8 v8; unsigned int u[4]; } x;
    x.v8 = v;
    #pragma unroll
    for (int i = 0; i < 4; i++) x.u[i] = (x.u[i] >> 16) | (x.u[i] << 16);
    return x.v8;
}
__device__ inline bf16x8 ldI(const unsigned short* buf, int row, int g, int q) {
    return *(const bf16x8*)&buf[row * IST + g * 32 + q * 8];
}
__device__ inline void mmQ(f32x4 (&out)[2][2],
                           const unsigned short* bufA, const unsigned short* bufB,
                           int ar0, int br0, int c, int q, bool share) {
    bf16x8 a[2][4], as[2][4];
    #pragma unroll
    for (int rt = 0; rt < 2; rt++)
        #pragma unroll
        for (int g = 0; g < 4; g++) {
            a[rt][g] = ldI(bufA, ar0 + 16 * rt + c, g, q);
            as[rt][g] = swap16(a[rt][g]);
        }
    #pragma unroll
    for (int ctl = 0; ctl < 2; ctl++) {
        bf16x8 b[4];
        if (share && ar0 == br0) {
            #pragma unroll
            for (int g = 0; g < 4; g++) b[g] = a[ctl][g];
        } else {
            #pragma unroll
            for (int g = 0; g < 4; g++) b[g] = ldI(bufB, br0 + 16 * ctl + c, g, q);
        }
        #pragma unroll
        for (int rt = 0; rt < 2; rt++) {
            f32x4 acc = {0.f, 0.f, 0.f, 0.f};
            #pragma unroll
            for (int g = 0; g < 4; g++) {
                acc = __builtin_amdgcn_mfma_f32_16x16x32_bf16(a[rt][g], b[g], acc, 0, 0, 0);
                acc = __builtin_amdgcn_mfma_f32_16x16x32_bf16(as[rt][g], b[g], acc, 0, 0, 0);
            }
            out[rt][ctl] = acc;
        }
    }
}
__device__ inline void writeRowQ(unsigned short* buf, const f32x4 (&M)[2][2],
                                 int ar0, int br0, int q, int c) {
    #pragma unroll
    for (int rt = 0; rt < 2; rt++)
        #pragma unroll
        for (int ctl = 0; ctl < 2; ctl++)
            #pragma unroll
            for (int r = 0; r < 4; r++) {
                unsigned short h, l;
                split2(M[rt][ctl][r], h, l);
                *(unsigned int*)&buf[(ar0 + 16 * rt + 4 * q + r) * IST + 2 * (br0 + 16 * ctl + c)] =
                    (unsigned)h | ((unsigned)l << 16);
            }
}
__device__ inline void writeColQ(unsigned short* buf, const f32x4 (&M)[2][2],
                                 int ar0, int br0, int q, int c) {
    #pragma unroll
    for (int rt = 0; rt < 2; rt++)
        #pragma unroll
        for (int ctl = 0; ctl < 2; ctl++) {
            unsigned int d[4];
            #pragma unroll
            for (int r = 0; r < 4; r++) {
                unsigned short h, l;
                split2(M[rt][ctl][r], h, l);
                d[r] = (unsigned)h | ((unsigned)l << 16);
            }
            *(uint4*)&buf[(br0 + 16 * ctl + c) * IST + 2 * (ar0 + 16 * rt + 4 * q)] =
                make_uint4(d[0], d[1], d[2], d[3]);
        }
}

__global__ __launch_bounds__(256, 3) void polar_kernel(const float* __restrict__ chunkS,
                                                       float* __restrict__ Z) {
    __shared__ __align__(16) unsigned short Xi[64 * IST];
    __shared__ __align__(16) unsigned short Xti[64 * IST];
    __shared__ __align__(16) unsigned short Yi[64 * IST];
    __shared__ float red[4];
    int tid = threadIdx.x;
    int w = tid >> 6, lane = tid & 63;
    int q = lane >> 4, c = lane & 15;
    int ar0 = (w >> 1) * 32, br0 = (w & 1) * 32;
    size_t base = (size_t)blockIdx.x * 4096;

    f32x4 Xc[2][2];
    float ss = 0.f;
    #pragma unroll
    for (int rt = 0; rt < 2; rt++)
        #pragma unroll
        for (int ctl = 0; ctl < 2; ctl++)
            #pragma unroll
            for (int r = 0; r < 4; r++) {
                float v = chunkS[base + (size_t)(ar0 + 16 * rt + 4 * q + r) * 64 + br0 + 16 * ctl + c];
                Xc[rt][ctl][r] = v;
                ss += v * v;
            }
    ss += __shfl_xor(ss, 1);  ss += __shfl_xor(ss, 2);  ss += __shfl_xor(ss, 4);
    ss += __shfl_xor(ss, 8);  ss += __shfl_xor(ss, 16); ss += __shfl_xor(ss, 32);
    if (lane == 0) red[w] = ss;
    __syncthreads();
    float sc = 1.f / (sqrtf(red[0] + red[1] + red[2] + red[3]) + 1e-7f);
    #pragma unroll
    for (int rt = 0; rt < 2; rt++)
        #pragma unroll
        for (int ctl = 0; ctl < 2; ctl++)
            #pragma unroll
            for (int r = 0; r < 4; r++) Xc[rt][ctl][r] *= sc;
    writeRowQ(Xi, Xc, ar0, br0, q, c);
    writeColQ(Xti, Xc, ar0, br0, q, c);
    __syncthreads();

    const float na = 3.4445f, nb = -4.7750f, ncf = 2.0315f;
    f32x4 Yc[2][2], Tc[2][2];
    for (int it = 0; it < NS_; ++it) {
        mmQ(Yc, Xi, Xi, ar0, br0, c, q, true);
        writeRowQ(Yi, Yc, ar0, br0, q, c);
        __syncthreads();   // b1: Yi complete; Xi reads done
        mmQ(Tc, Yi, Yi, ar0, br0, c, q, true);
        #pragma unroll
        for (int rt = 0; rt < 2; rt++)
            #pragma unroll
            for (int ctl = 0; ctl < 2; ctl++)
                #pragma unroll
                for (int r = 0; r < 4; r++)
                    Yc[rt][ctl][r] = nb * Yc[rt][ctl][r] + ncf * Tc[rt][ctl][r];
        __syncthreads();   // b2: Yi reads done -> safe to overwrite with W
        writeRowQ(Yi, Yc, ar0, br0, q, c);
        __syncthreads();   // b3: W complete (cross-wave A reads in P3)
        mmQ(Tc, Yi, Xti, ar0, br0, c, q, false);
        #pragma unroll
        for (int rt = 0; rt < 2; rt++)
            #pragma unroll
            for (int ctl = 0; ctl < 2; ctl++)
                #pragma unroll
                for (int r = 0; r < 4; r++)
                    Xc[rt][ctl][r] = na * Xc[rt][ctl][r] + Tc[rt][ctl][r];
        if (it != NS_ - 1) {
            writeRowQ(Xi, Xc, ar0, br0, q, c);
            __syncthreads();                      // b4: Xti reads done; Xi visible
            writeColQ(Xti, Xc, ar0, br0, q, c);
        }
    }
    #pragma unroll
    for (int rt = 0; rt < 2; rt++)
        #pragma unroll
        for (int ctl = 0; ctl < 2; ctl++)
            #pragma unroll
            for (int r = 0; r < 4; r++)
                Z[base + (size_t)(ar0 + 16 * rt + 4 * q + r) * 64 + br0 + 16 * ctl + c] = Xc[rt][ctl][r];
}

// ---------------------------------------------------------------------------
// Fused m_y(ch) + chunk_s(ch+1), RE-TILED for occupancy: 1024 blocks x 128
// threads, vtile = 2 M-rows, 1 matrix element per thread. All global accesses
// 256 B/wave coalesced. y written directly as hi/lo bf16 (epilogue GEMM A).
// ---------------------------------------------------------------------------
__global__ __launch_bounds__(128) void fused_my_cs(const float* __restrict__ Zb,
                                                   const float* __restrict__ qbuf,
                                                   const float* __restrict__ kbuf,
                                                   const float* __restrict__ vbuf,
                                                   const float* __restrict__ gates,
                                                   float* __restrict__ Mc,
                                                   float* __restrict__ Sc,
                                                   float* __restrict__ chunkS,
                                                   unsigned short* __restrict__ ybh,
                                                   unsigned short* __restrict__ ybl,
                                                   int chunk) {
    __shared__ float buf[CS_][68];     // q chunk, then K chunk
    __shared__ float Mrow[2][68];
    __shared__ float errS[CS_][2];
    __shared__ float alS[CS_], thS[CS_], etS[CS_], gmS[CS_];
    int tid = threadIdx.x, idx = blockIdx.x;
    int vt = idx & 31, h = (idx >> 5) & 15, b = idx >> 9;
    int c0t = chunk * CS_;
    {   // stage q chunk: thread covers row tid&63, col half (tid>>6)*32..
        int row = tid & 63, half = tid >> 6;
        const float* src = &qbuf[((size_t)(b * T_ + c0t + row) * H_ + h) * D_ + half * 32];
        #pragma unroll
        for (int i = 0; i < 8; i++)
            *(float4*)&buf[row][half * 32 + i * 4] = *(const float4*)&src[i * 4];
    }
    if (tid < CS_) alS[tid] = gates[0 * (B_ * T_ * H_) + (b * T_ + c0t + tid) * H_ + h];
    __syncthreads();
    int vl = tid >> 6, k = tid & 63;          // wave = one M-row
    size_t mIdx = ((size_t)(b * H_ + h)) * 4096 + (vt * 2 + vl) * 64 + k;
    size_t zrow = ((size_t)(b * H_ + h) * CS_) * 4096 + (vt * 2 + vl) * 64 + k;
    float M0 = Mc[mIdx];
    float z = Zb[zrow];
    #pragma unroll 4
    for (int c = 0; c < CS_; c++) {
        int cn = (c + 1) & (CS_ - 1);
        float znext = Zb[zrow + (size_t)cn * 4096];
        M0 = alS[c] * M0 + z;
        float p = M0 * buf[c][k];
        p += __shfl_xor(p, 1);  p += __shfl_xor(p, 2);  p += __shfl_xor(p, 4);
        p += __shfl_xor(p, 8);  p += __shfl_xor(p, 16); p += __shfl_xor(p, 32);
        if (k == 0) {
            size_t yo = ((size_t)(b * T_ + c0t + c) * H_ + h) * D_ + vt * 2 + vl;
            unsigned short hh, ll;
            split2(p, hh, ll);
            ybh[yo] = hh; ybl[yo] = ll;
        }
        z = znext;
    }
    Mc[mIdx] = M0;
    if (chunk + 1 >= NC_) return;
    int c1t = c0t + CS_;
    __syncthreads();   // everyone done with buf (q)
    Mrow[vl][k] = M0;
    {   // stage K chunk ch+1
        int row = tid & 63, half = tid >> 6;
        const float* src = &kbuf[((size_t)(b * T_ + c1t + row) * H_ + h) * D_ + half * 32];
        #pragma unroll
        for (int i = 0; i < 8; i++)
            *(float4*)&buf[row][half * 32 + i * 4] = *(const float4*)&src[i * 4];
    }
    if (tid < CS_) {
        thS[tid] = gates[2 * (B_ * T_ * H_) + (b * T_ + c1t + tid) * H_ + h];
        gmS[tid] = gates[3 * (B_ * T_ * H_) + (b * T_ + c1t + tid) * H_ + h];
    } else {
        int t = tid - CS_;
        etS[t] = gates[1 * (B_ * T_ * H_) + (b * T_ + c1t + t) * H_ + h];
    }
    __syncthreads();
    {   // err[t][v] = M_row_v . K[t] - v ; thread = (t = tid>>1, v = tid&1)
        int t = tid >> 1, v0 = tid & 1;
        float s = 0.f;
        #pragma unroll
        for (int kk = 0; kk < 64; kk += 4) {
            float4 kv = *(float4*)&buf[t][kk];
            float4 mv = *(float4*)&Mrow[v0][kk];
            s += kv.x * mv.x + kv.y * mv.y + kv.z * mv.z + kv.w * mv.w;
        }
        errS[t][v0] = s - vbuf[((size_t)(b * T_ + c1t + t) * H_ + h) * D_ + vt * 2 + v0];
    }
    __syncthreads();
    float S0 = Sc[mIdx];
    float ring[16] = {};
    float cum = 0.f;
    for (int cb = 0; cb < 4; ++cb) {
        #pragma unroll
        for (int ci = 0; ci < 16; ++ci) {
            int cc = cb * 16 + ci;
            float er = 2.f * errS[cc][vl];
            cum += gmS[cc] * er * buf[cc][k];
            float uw = cum - ring[ci];
            ring[ci] = cum;
            S0 = thS[cc] * S0 - etS[cc] * uw;
            chunkS[((size_t)((b * H_ + h) * CS_ + cc)) * 4096 + (vt * 2 + vl) * 64 + k] = S0;
        }
    }
    Sc[mIdx] = S0;
}

// ---------------------------------------------------------------------------
extern "C" void kernel_launch(void* const* d_in, const int* in_sizes, int n_in,
                              void* d_out, int out_size, void* d_ws, size_t ws_size,
                              hipStream_t stream) {
    (void)in_sizes; (void)n_in; (void)out_size; (void)ws_size;
    const float* x     = (const float*)d_in[0];
    const float* Wq    = (const float*)d_in[1];
    const float* Wk    = (const float*)d_in[2];
    const float* Wv    = (const float*)d_in[3];
    const float* Wproj = (const float*)d_in[4];
    const float* cqw   = (const float*)d_in[5];
    const float* cqb   = (const float*)d_in[6];
    const float* ckw   = (const float*)d_in[7];
    const float* ckb   = (const float*)d_in[8];
    const float* cvw   = (const float*)d_in[9];
    const float* cvb   = (const float*)d_in[10];
    const float* Wa    = (const float*)d_in[11];
    const float* We    = (const float*)d_in[12];
    const float* Wt    = (const float*)d_in[13];
    const float* Wg    = (const float*)d_in[14];

    float* ws  = (float*)d_ws;
    float* Qb  = ws;                      // 4194304 floats (B,T,C)
    float* Kb  = Qb + 4194304;
    float* Vb  = Kb + 4194304;
    float* Yb  = Vb + 4194304;            // reused as bf16 hi/lo y buffers
    float* Gb  = Yb + 4194304;            // 262144 (4,B,T,H)
    float* Mc  = Gb + 262144;             // 131072 (B,H,D,D)
    float* Sc  = Mc + 131072;             // 131072
    float* CSb = Sc + 131072;             // 8388608 (B,H,CS,D,D)
    float* Zb  = CSb + 8388608;           // 8388608
    unsigned short* su = (unsigned short*)CSb;
    unsigned short* xh  = su;
    unsigned short* xl  = su + 4194304;
    unsigned short* Wqh = su + 8388608,  *Wql = su + 9437184;
    unsigned short* Wkh = su + 10485760, *Wkl = su + 11534336;
    unsigned short* Wvh = su + 12582912, *Wvl = su + 13631488;
    unsigned short* Ybh = (unsigned short*)Yb;        // (B*T, C) bf16 hi
    unsigned short* Ybl = Ybh + 4194304;              // (B*T, C) bf16 lo
    float* bufA = Zb;

    hipMemsetAsync(Mc, 0, 2 * 131072 * sizeof(float), stream);

    split_kernel<<<4096, 256, 0, stream>>>(x, xh, xl, 4194304);
    split_kernel<<<1024, 256, 0, stream>>>(Wq, Wqh, Wql, 1048576);
    split_kernel<<<1024, 256, 0, stream>>>(Wk, Wkh, Wkl, 1048576);
    split_kernel<<<1024, 256, 0, stream>>>(Wv, Wvh, Wvl, 1048576);

    dim3 gs(C_ / 128, (B_ * T_) / 128);
    gemm_split<<<gs, 256, 0, stream>>>(xh, xl, Wqh, Wql, bufA);
    conv_kernel<<<B_ * T_, 256, 0, stream>>>(bufA, cqw, cqb, Qb, 1);
    gemm_split<<<gs, 256, 0, stream>>>(xh, xl, Wkh, Wkl, bufA);
    conv_kernel<<<B_ * T_, 256, 0, stream>>>(bufA, ckw, ckb, Kb, 2);
    gemm_split<<<gs, 256, 0, stream>>>(xh, xl, Wvh, Wvl, bufA);
    conv_kernel<<<B_ * T_, 256, 0, stream>>>(bufA, cvw, cvb, Vb, 0);
    gates_kernel<<<B_ * T_, 256, 0, stream>>>(x, Wa, We, Wt, Wg, Gb);

    chunk_s_kernel<<<B_ * H_ * 8, 256, 0, stream>>>(Kb, Vb, Gb, Mc, Sc, CSb, 0);
    for (int ch = 0; ch < NC_; ++ch) {
        polar_kernel<<<B_ * H_ * CS_, 256, 0, stream>>>(CSb, Zb);
        fused_my_cs<<<B_ * H_ * 32, 128, 0, stream>>>(Zb, Qb, Kb, Vb, Gb, Mc, Sc, CSb,
                                                      Ybh, Ybl, ch);
    }

    // final projection: y already in bf16 hi/lo; split only Wproj
    unsigned short* Wph = su + 8388608, *Wpl = su + 9437184;
    split_kernel<<<1024, 256, 0, stream>>>(Wproj, Wph, Wpl, 1048576);
    gemm_split<<<gs, 256, 0, stream>>>(Ybh, Ybl, Wph, Wpl, (float*)d_out);
}